// Round 20
// baseline (67.873 us; speedup 1.0000x reference)
//
#include <hip/hip_runtime.h>

// LocalCrossCorrelation3D: I,J (2,1,96,192,192) fp32 -> (loss[2], cc[2,81,192,192])
// Window (16,9,9): depth valid (96->81), h/w zero-padded +-4.
// K1 = ZERO-BARRIER wave-independent: 256-thr blocks = 4 waves, each wave
// owns a 56-output w-tile (+8 halo lanes, redundant) with a PRIVATE LDS
// slice; depth sliding sum in regs (1-ahead prefetch); 9-tap w-box as two
// 3-tap stages through wave-synchronous LDS. 32 waves/CU (2x round-17).
// K2 = h sliding box, full unroll + static ring, CH=24, spread-slot atomics.
// K3 = slot reduce.

constexpr int N = 2, D = 96, H = 192, W = 192;
constexpr int OD = 81;            // D - 16 + 1
constexpr int KD = 16;
constexpr int HWp = H * W;        // 36864
constexpr float INV_WIN = 1.0f / 1296.0f;
constexpr float EPS_NZ = 3.0590232050182579e-07f;  // e^-15
constexpr int CH = 24;            // h-chunk per block in K2 (192/24 = 8)
constexpr int ODPB = 14;          // od-range per K1 block

__device__ __forceinline__ unsigned bf16rne(float f) {  // f32 -> bf16 bits (RNE)
  unsigned u = __float_as_uint(f);
  return (u + 0x7fffu + ((u >> 16) & 1u)) >> 16;
}
__device__ __forceinline__ float bf16tof(unsigned h) {  // bf16 bits -> f32
  return __uint_as_float(h << 16);
}

// ---------------------------------------------------------------------------
// K1. 4 waves/block; wave t covers columns wcol = t*56 + lane - 4 (lanes
// 4..59 are outputs; l<4 / l>=60 redundant halo). Per od:
//   x[l] = 5-ch depth sums (post-add snapshot) -> private LDS slice;
//   stage1: A[l] = x[l-1]+x[l]+x[l+1]  (own x in regs);
//   stage2: S[l] = A[l-3]+A[l]+A[l+3]  (own A in regs).
// Wrap ((l+-k)&63) garbage reaches only A[0]/A[63], consumed only by lanes
// 3/60 -> non-output lanes. Out-of-range columns load 0 (zero-pad).
// NO barriers: each wave touches only its own LDS slice; DS ops from a
// single wave execute in order (compiler inserts lgkmcnt waits).
// ws layout: [n][odi][h][w] x 3 uints (bf16 pairs: (s0,s1),(s2,s3),(s4,_)).
__global__ __launch_bounds__(256)
void k_dw(const float* __restrict__ I, const float* __restrict__ J,
          unsigned* __restrict__ ws, int od0, int c, int odcStride) {
  const int h = blockIdx.x;
  const int n = blockIdx.z;
  const int os = od0 + blockIdx.y * ODPB;
  int oe = od0 + c; if (os + ODPB < oe) oe = os + ODPB;
  if (os >= oe) return;

  const int lane = threadIdx.x & 63;
  const int tile = threadIdx.x >> 6;          // 0..3
  const int wcol = tile * 56 + lane - 4;      // -4 .. 227
  const bool colOK = (wcol >= 0) && (wcol < W);
  const bool stOK  = (lane >= 4) && (lane < 60) && (wcol < W);

  __shared__ float4 x4[4][64]; __shared__ float x1[4][64];
  __shared__ float4 a4[4][64]; __shared__ float a1[4][64];

  const size_t colBase = ((size_t)n * D * H + h) * (size_t)W + wcol;
  const float* Ip = I + colBase;
  const float* Jp = J + colBase;
  unsigned* wbase = ws + ((size_t)n * odcStride * HWp + (size_t)h * W + wcol) * 3;

  const int lm1 = (lane - 1) & 63, lp1 = (lane + 1) & 63;
  const int lm3 = (lane - 3) & 63, lp3 = (lane + 3) & 63;

  // warm-up: accumulate slices [os, os+KD-2] (15 slices)
  float sI = 0.f, sJ = 0.f, sII = 0.f, sJJ = 0.f, sIJ = 0.f;
  for (int d = os; d < os + KD - 1; ++d) {
    const float iv = colOK ? Ip[(size_t)d * HWp] : 0.f;
    const float jv = colOK ? Jp[(size_t)d * HWp] : 0.f;
    sI += iv; sJ += jv;
    sII += iv * iv; sJJ += jv * jv; sIJ += iv * jv;
  }

  // prefetch first round: entering od+15, leaving od
  float eI = colOK ? Ip[(size_t)(os + KD - 1) * HWp] : 0.f;
  float eJ = colOK ? Jp[(size_t)(os + KD - 1) * HWp] : 0.f;
  float lI = colOK ? Ip[(size_t)os * HWp] : 0.f;
  float lJ = colOK ? Jp[(size_t)os * HWp] : 0.f;

  for (int od = os; od < oe; ++od) {
    const float ceI = eI, ceJ = eJ, clI = lI, clJ = lJ;
    const int odn = od + 1;
    if (odn < oe) {   // prefetch next round (awaited next iteration)
      eI = colOK ? Ip[(size_t)(odn + KD - 1) * HWp] : 0.f;
      eJ = colOK ? Jp[(size_t)(odn + KD - 1) * HWp] : 0.f;
      lI = colOK ? Ip[(size_t)odn * HWp] : 0.f;
      lJ = colOK ? Jp[(size_t)odn * HWp] : 0.f;
    }
    // snapshot (post-add)
    sI += ceI; sJ += ceJ;
    sII += ceI * ceI; sJJ += ceJ * ceJ; sIJ += ceI * ceJ;
    const float cI = sI, cJ = sJ, cII = sII, cJJ = sJJ, cIJ = sIJ;
    x4[tile][lane] = make_float4(cI, cJ, cII, cJJ); x1[tile][lane] = cIJ;
    sI -= clI; sJ -= clJ;
    sII -= clI * clI; sJJ -= clJ * clJ; sIJ -= clI * clJ;

    // stage 1: A = x[l-1] + x(own) + x[l+1]
    const float4 m0 = x4[tile][lm1], m2 = x4[tile][lp1];
    const float  p0 = x1[tile][lm1], p2 = x1[tile][lp1];
    const float aI  = m0.x + cI  + m2.x;
    const float aJ  = m0.y + cJ  + m2.y;
    const float aII = m0.z + cII + m2.z;
    const float aJJ = m0.w + cJJ + m2.w;
    const float aIJ = p0   + cIJ + p2;
    a4[tile][lane] = make_float4(aI, aJ, aII, aJJ); a1[tile][lane] = aIJ;

    // stage 2: S = A[l-3] + A(own) + A[l+3]
    const float4 b0 = a4[tile][lm3], b2 = a4[tile][lp3];
    const float  q0 = a1[tile][lm3], q2 = a1[tile][lp3];
    const float r0 = b0.x + aI  + b2.x;
    const float r1 = b0.y + aJ  + b2.y;
    const float r2 = b0.z + aII + b2.z;
    const float r3 = b0.w + aJJ + b2.w;
    const float r4 = q0   + aIJ + q2;

    if (stOK) {
      unsigned* o = wbase + (size_t)(od - od0) * HWp * 3;
      o[0] = bf16rne(r0) | (bf16rne(r1) << 16);
      o[1] = bf16rne(r2) | (bf16rne(r3) << 16);
      o[2] = bf16rne(r4);
    }
  }
}

// ---------------------------------------------------------------------------
// K2: 9-wide h box via fully-unrolled stream with an 8-deep static ring
// (no subtract re-loads) + one-ahead prefetch; cc formula + loss reduction.
// Loss partial -> one of 32 spread slots per batch (atomic line-spread).
// Block: 192 threads = w-row, grid (od, h-chunk of 24, n).
__global__ __launch_bounds__(192)
void k_hcc(const unsigned* __restrict__ ws, float* __restrict__ cc,
           float* __restrict__ acc, int od0, int odcStride) {
  const int odi = blockIdx.x;
  const int od = od0 + odi;
  const int h0 = blockIdx.y * CH;
  const int n = blockIdx.z;
  const int w = threadIdx.x;
  const unsigned* base =
      ws + ((size_t)n * odcStride * HWp + (size_t)odi * HWp + w) * 3;
  float* ccp = cc + ((size_t)n * OD + od) * (size_t)HWp + w;

  float s0 = 0.f, s1 = 0.f, s2 = 0.f, s3 = 0.f, s4 = 0.f;
  float lsum = 0.f;
  uint3 hist[8];
  const uint3 z3 = make_uint3(0u, 0u, 0u);

  // prefetch t=0 row
  uint3 vN = z3;
  {
    const int hin = h0 - 4;
    if (hin >= 0) vN = *(const uint3*)(base + (size_t)hin * W * 3);
  }
#pragma unroll
  for (int t = 0; t < CH + 8; ++t) {
    const uint3 v = vN;
    // prefetch next row
    if (t + 1 < CH + 8) {
      const int hn = h0 - 4 + t + 1;
      vN = (hn >= 0 && hn < H) ? *(const uint3*)(base + (size_t)hn * W * 3) : z3;
    }
    s0 += bf16tof(v.x & 0xffffu); s1 += bf16tof(v.x >> 16);
    s2 += bf16tof(v.y & 0xffffu); s3 += bf16tof(v.y >> 16);
    s4 += bf16tof(v.z & 0xffffu);
    if (t >= 8) {
      const int h = h0 + t - 8;
      const float cross = s4 - s0 * s1 * INV_WIN;
      const float vI = s2 - s0 * s0 * INV_WIN;
      const float vJ = s3 - s1 * s1 * INV_WIN;
      const float prod = vI * vJ;
      const float c = (prod > EPS_NZ) ? (cross * cross) / (prod + EPS_NZ)
                                      : 1.0f / (1.0f + EPS_NZ);
      ccp[(size_t)h * W] = c;
      lsum += c;
      const uint3 q = hist[t & 7];       // row that entered 8 steps ago
      s0 -= bf16tof(q.x & 0xffffu); s1 -= bf16tof(q.x >> 16);
      s2 -= bf16tof(q.y & 0xffffu); s3 -= bf16tof(q.y >> 16);
      s4 -= bf16tof(q.z & 0xffffu);
    }
    hist[t & 7] = v;                     // static index (full unroll)
  }
  __shared__ float red[3];
#pragma unroll
  for (int off = 32; off > 0; off >>= 1) lsum += __shfl_xor(lsum, off, 64);
  if ((threadIdx.x & 63) == 0) red[threadIdx.x >> 6] = lsum;
  __syncthreads();
  if (threadIdx.x == 0)
    atomicAdd(acc + n * 32 + (odi & 31), red[0] + red[1] + red[2]);
}

// ---------------------------------------------------------------------------
// K3: reduce the 64 spread slots (32 per batch) -> loss.
__global__ void k_fin(const float* __restrict__ acc, float* __restrict__ out) {
  const int t = threadIdx.x;            // 64 threads
  float v = acc[t];                     // slots [n*32 + k]
#pragma unroll
  for (int off = 16; off > 0; off >>= 1) v += __shfl_xor(v, off, 32);
  if (t == 0)  out[0] = 1.0f - v * (1.0f / 2985984.0f);
  if (t == 32) out[1] = 1.0f - v * (1.0f / 2985984.0f);
}

// ---------------------------------------------------------------------------
extern "C" void kernel_launch(void* const* d_in, const int* in_sizes, int n_in,
                              void* d_out, int out_size, void* d_ws,
                              size_t ws_size, hipStream_t stream) {
  const float* I = (const float*)d_in[0];
  const float* J = (const float*)d_in[1];
  float* out = (float*)d_out;
  float* acc = (float*)d_ws;                       // 64 fp32 spread slots
  unsigned* planes = (unsigned*)((char*)d_ws + 256);

  hipMemsetAsync(d_ws, 0, 64 * sizeof(float), stream);

  // adaptive od-chunking: packed voxel = 12B, two n-slabs
  const size_t perOdPerN = (size_t)HWp * 12;       // 442368 B
  size_t avail = (ws_size > 256) ? (ws_size - 256) : 0;
  long long odcMax = (long long)(avail / (2 * perOdPerN));
  if (odcMax < 1) odcMax = 1;
  if (odcMax > OD) odcMax = OD;
  const int odc = (int)odcMax;                     // slab stride (od entries)

  float* ccOut = out + 2;
  for (int od0 = 0; od0 < OD; od0 += odc) {
    const int c = (odc < OD - od0) ? odc : (OD - od0);
    const int S = (c + ODPB - 1) / ODPB;
    hipLaunchKernelGGL(k_dw, dim3(H, S, N), dim3(256), 0, stream,
                       I, J, planes, od0, c, odc);
    hipLaunchKernelGGL(k_hcc, dim3(c, H / CH, N), dim3(192), 0, stream,
                       planes, ccOut, acc, od0, odc);
  }
  hipLaunchKernelGGL(k_fin, dim3(1), dim3(64), 0, stream, acc, out);
}